// Round 4
// baseline (150.122 us; speedup 1.0000x reference)
//
#include <hip/hip_runtime.h>
#include <stdint.h>
#include <math.h>

#define BATCH 16
#define NNODE 2048
#define DDIM  64
#define NEDGE 32768
#define SEG   32            // slots per quarter-scan segment (mean 8; P(>32)~1e-11)
#define SLOTS 128           // 4*SEG slots per row
#define NROWS (BATCH*NNODE) // 32768
#define RPB   128           // rows per k_build block (512-thread blocks)

// ---------------- kernel 1: LDS-bucketed edge build (quarter-scan) ------
// (verbatim — known-good)
__global__ void k_build(const int* __restrict__ ei, const float* __restrict__ m,
                        uint32_t* __restrict__ cnt4, uint2* __restrict__ entries) {
    __shared__ uint32_t cntS[RPB];
    __shared__ uint32_t keyS[RPB][SEG];   // col | prio<<11
    __shared__ float    valS[RPB][SEG];

    int b  = blockIdx.x & 15;             // batch (XCD-pinned)
    int gh = blockIdx.x >> 4;             // 0..63: row-group*4 + quarter
    int r0 = (gh >> 2) * RPB;             // first owned row
    int q  = gh & 3;                      // which quarter of the edge list
    int t  = threadIdx.x;                 // 0..511

    if (t < RPB) cntS[t] = 0u;
    __syncthreads();

    const int*   eb = ei + (size_t)b * 2 * NEDGE;
    const float* mb = m  + (size_t)b * NEDGE;
    int e0 = q * (NEDGE / 4);

    for (int i = 0; i < 4; ++i) {                  // 4 x 2048 edges (quarter)
        int e4 = e0 + i * 2048 + t * 4;
        int4   s4 = *(const int4*)(eb + e4);
        int4   d4 = *(const int4*)(eb + NEDGE + e4);
        float4 m4 = *(const float4*)(mb + e4);
        #pragma unroll
        for (int j = 0; j < 4; ++j) {
            int   src = j == 0 ? s4.x : j == 1 ? s4.y : j == 2 ? s4.z : s4.w;
            int   dst = j == 0 ? d4.x : j == 1 ? d4.y : j == 2 ? d4.z : d4.w;
            float mv  = j == 0 ? m4.x : j == 1 ? m4.y : j == 2 ? m4.z : m4.w;
            int e  = e4 + j;
            int rs = src - r0;
            if ((unsigned)rs < RPB) {              // row src, col dst, prio e
                uint32_t p = atomicAdd(&cntS[rs], 1u);
                if (p < SEG) { keyS[rs][p] = (uint32_t)dst | ((uint32_t)e << 11); valS[rs][p] = mv; }
            }
            int rd = dst - r0;
            if ((unsigned)rd < RPB) {              // row dst, col src, prio E+e
                uint32_t p = atomicAdd(&cntS[rd], 1u);
                if (p < SEG) { keyS[rd][p] = (uint32_t)src | ((uint32_t)(NEDGE + e) << 11); valS[rd][p] = mv; }
            }
        }
    }
    __syncthreads();

    // coalesced write-out: 8 waves x 16 rows; lanes 0-31 row 2rr, 32-63 row 2rr+1
    int lane = t & 63;
    int wid  = t >> 6;                    // 0..7
    int pos  = lane & 31;
    int sub  = lane >> 5;
    for (int rr = 0; rr < 8; ++rr) {
        int r  = wid * 16 + rr * 2 + sub;
        int rg = b * NNODE + r0 + r;
        int k  = (int)min(cntS[r], (uint32_t)SEG);
        size_t base = (size_t)rg * SLOTS + q * SEG;
        if (pos < k)
            entries[base + pos] = make_uint2(keyS[r][pos], __float_as_uint(valS[r][pos]));
        if (pos == 0) cnt4[rg * 4 + q] = (uint32_t)k;
    }
}

// ---------------- kernel 2: per-row dedupe via LDS scatter-max ----------
// (verbatim from R2 — the -23us win)
__global__ void k_dedupe(const uint32_t* __restrict__ cnt4, uint2* __restrict__ entries,
                         uint32_t* __restrict__ cnt_fin,
                         float* __restrict__ dis, float* __restrict__ self) {
    __shared__ uint32_t tbl[4][NNODE];    // 32 KB: one table per wave
    int b    = blockIdx.x & 15;
    int wv   = threadIdx.x >> 6;
    int w    = b * NNODE + (blockIdx.x >> 4) * 4 + wv;
    int lane = threadIdx.x & 63;
    uint32_t* T = tbl[wv];
    uint4 kq = ((const uint4*)cnt4)[w];
    int k0 = (int)kq.x, k1 = (int)kq.y, k2 = (int)kq.z, k3 = (int)kq.w;
    size_t base = (size_t)w * SLOTS;
    int pos = lane & 31;
    int klo = (lane < 32) ? k0 : k1;
    int khi = (lane < 32) ? k2 : k3;

    uint32_t key0 = 0u, key1 = 0u;
    float v0 = 0.f, v1 = 0.f;
    bool a0 = pos < klo;
    bool a1 = pos < khi;
    if (a0) { uint2 kv = entries[base + lane];      key0 = kv.x; v0 = __uint_as_float(kv.y); }
    if (a1) { uint2 kv = entries[base + 64 + lane]; key1 = kv.x; v1 = __uint_as_float(kv.y); }
    uint32_t c0 = key0 & 2047u, p0 = key0 >> 11;
    uint32_t c1 = key1 & 2047u, p1 = key1 >> 11;

    // clear only the touched slots (LDS is uninitialized garbage otherwise)
    if (a0) T[c0] = 0u;
    if (a1) T[c1] = 0u;
    // scatter-max the priorities
    if (a0) atomicMax(&T[c0], p0);
    if (a1) atomicMax(&T[c1], p1);
    // read back: survivor iff my prio won
    if (a0) a0 = (T[c0] == p0);
    if (a1) a1 = (T[c1] == p1);

    float sum = (a0 ? v0 : 0.f) + (a1 ? v1 : 0.f);
    for (int off = 32; off; off >>= 1) sum += __shfl_xor(sum, off, 64);
    float deg = fmaxf(1.0f + sum, 1e-6f);          // +1: identity diagonal
    if (lane == 0) {
        float di = 1.0f / sqrtf(deg);
        dis[w]  = di;
        self[w] = di * di;
    }

    unsigned long long m0 = __ballot(a0);
    unsigned long long m1 = __ballot(a1);
    unsigned long long below = (1ull << lane) - 1ull;
    int n0 = __popcll(m0);
    if (a0) entries[base + __popcll(m0 & below)]      = make_uint2(key0, __float_as_uint(v0));
    if (a1) entries[base + n0 + __popcll(m1 & below)] = make_uint2(key1, __float_as_uint(v1));
    if (lane == 0) cnt_fin[w] = (uint32_t)(n0 + __popcll(m1));
}

// ---------------- kernel 3: fused SpMM + (X @ W^T) + optional GELU ------
// v4: paired gather. Entries (2p,2p+1) served by ONE dwordx2 load: lanes
// 0-31 take entry 2p's X-row (2 floats/lane), lanes 32-63 entry 2p+1's.
// Per-half scalars (offset, weight) come from ds_bpermute(hi*4 + 8p) —
// 2 inst/pair vs 4 readlane + 2 selects. Lanes >= k carry col=0/w=0 from
// setup, so odd-k tails are numerically free. Packed (even/odd feature)
// accumulators are combined with shfl_xor(32) and converted to the scalar
// lane=feature layout with 2 bpermute + cndmask. k>64 rows (P~1e-7) fall
// back to the scalar path. Halves gather VMEM ops, -24% wave instructions.
__global__ void k_layer(const float* __restrict__ Xin, const float* __restrict__ W,
                        float* __restrict__ Xout,
                        const uint32_t* __restrict__ cnt_fin, const uint2* __restrict__ entries,
                        const float* __restrict__ dis, const float* __restrict__ self,
                        int dogelu) {
    __shared__ float WT[64 * 65];     // WT[d*65+e] = W[e*64+d]; +1 pad: conflict-free
    int Lb = blockIdx.x;              // 4096 blocks
    int b  = Lb & 15;                 // batch -> XCD swizzle
    int rb = Lb >> 4;
    int t  = threadIdx.x;

    #pragma unroll
    for (int i = 0; i < 16; ++i) {
        int idx = i * 256 + t;
        WT[(idx & 63) * 65 + (idx >> 6)] = W[idx];
    }
    __syncthreads();

    int lane = t & 63;
    int wid  = t >> 6;
    const float* Xb   = Xin + (size_t)b * NNODE * DDIM;
    const char*  Xc   = (const char*)Xb + lane * 4;          // scalar-path base
    const char*  XcPK = (const char*)Xb + (lane & 31) * 8;   // packed-path base
    const float* disB = dis + (b << 11);

    int row0 = rb * 8 + wid * 2;
    int rg0  = b * NNODE + row0;
    uint32_t bsel = (uint32_t)(lane & 32) >> 3;   // 0 (lo half) or 4 (hi half)

    // ---- hoisted setup for BOTH rows ----
    uint32_t offAr[2], wAur[2], offBr[2], wBur[2];
    int      kkr[2];
    float    selfS[2];
    #pragma unroll
    for (int rr = 0; rr < 2; ++rr) {
        int rg = rg0 + rr;
        int k  = (int)cnt_fin[rg];
        kkr[rr] = k;
        size_t base = (size_t)rg * SLOTS;
        uint32_t kA = 0u, vA = 0u, kB = 0u, vB = 0u;
        if (lane < k)      { uint2 kv = entries[base + lane];      kA = kv.x; vA = kv.y; }
        if (lane + 64 < k) { uint2 kv = entries[base + 64 + lane]; kB = kv.x; vB = kv.y; }
        float dr = disB[row0 + rr];
        int   colA = (int)(kA & 2047u);
        offAr[rr] = (uint32_t)colA << 8;
        wAur[rr]  = __float_as_uint(__uint_as_float(vA) * dr * disB[colA]);
        int   colB = (int)(kB & 2047u);
        offBr[rr] = (uint32_t)colB << 8;
        wBur[rr]  = __float_as_uint(__uint_as_float(vB) * dr * disB[colB]);
        selfS[rr] = self[rg];
    }

    float accv[2];
    #pragma unroll
    for (int rr = 0; rr < 2; ++rr) {
        int k = kkr[rr];
        int row = row0 + rr;
        uint32_t offA = offAr[rr], wAu = wAur[rr];

        if (k <= 64) {
            // ---------------- packed path ----------------
            // identity: lanes<32 carry it; hi lanes start at 0
            float2 xid = *(const float2*)((const char*)Xb + (uint32_t)row * 256 + (lane & 31) * 8);
            float idw = (lane < 32) ? selfS[rr] : 0.f;
            float al0 = idw * xid.x, ah0 = idw * xid.y;
            float al1 = 0.f, ah1 = 0.f, al2 = 0.f, ah2 = 0.f, al3 = 0.f, ah3 = 0.f;

            int npair = (k + 1) >> 1;
            int p = 0;
            for (; p + 8 <= npair; p += 8) {       // 8 paired loads in flight
                uint32_t o0, o1, o2, o3, o4, o5, o6, o7;
                float w0, w1, w2, w3, w4, w5, w6, w7;
                float2 x0, x1, x2, x3, x4, x5, x6, x7;
                #define GP(i, O, WW, XV) { \
                    O  = (uint32_t)__builtin_amdgcn_ds_bpermute((int)(bsel + 8u * (uint32_t)(p + i)), (int)offA); \
                    WW = __uint_as_float((uint32_t)__builtin_amdgcn_ds_bpermute((int)(bsel + 8u * (uint32_t)(p + i)), (int)wAu)); \
                    XV = *(const float2*)(XcPK + O); }
                GP(0, o0, w0, x0) GP(1, o1, w1, x1) GP(2, o2, w2, x2) GP(3, o3, w3, x3)
                GP(4, o4, w4, x4) GP(5, o5, w5, x5) GP(6, o6, w6, x6) GP(7, o7, w7, x7)
                #undef GP
                al0 = fmaf(w0, x0.x, al0); ah0 = fmaf(w0, x0.y, ah0);
                al1 = fmaf(w1, x1.x, al1); ah1 = fmaf(w1, x1.y, ah1);
                al2 = fmaf(w2, x2.x, al2); ah2 = fmaf(w2, x2.y, ah2);
                al3 = fmaf(w3, x3.x, al3); ah3 = fmaf(w3, x3.y, ah3);
                al0 = fmaf(w4, x4.x, al0); ah0 = fmaf(w4, x4.y, ah0);
                al1 = fmaf(w5, x5.x, al1); ah1 = fmaf(w5, x5.y, ah1);
                al2 = fmaf(w6, x6.x, al2); ah2 = fmaf(w6, x6.y, ah2);
                al3 = fmaf(w7, x7.x, al3); ah3 = fmaf(w7, x7.y, ah3);
            }
            for (; p < npair; ++p) {
                uint32_t o = (uint32_t)__builtin_amdgcn_ds_bpermute((int)(bsel + 8u * (uint32_t)p), (int)offA);
                float    w = __uint_as_float((uint32_t)__builtin_amdgcn_ds_bpermute((int)(bsel + 8u * (uint32_t)p), (int)wAu));
                float2   x = *(const float2*)(XcPK + o);
                al0 = fmaf(w, x.x, al0); ah0 = fmaf(w, x.y, ah0);
            }

            float slo = (al0 + al1) + (al2 + al3);
            float shi = (ah0 + ah1) + (ah2 + ah3);
            slo += __shfl_xor(slo, 32, 64);
            shi += __shfl_xor(shi, 32, 64);
            // convert packed (feature 2i in slo[i], 2i+1 in shi[i]) -> lane=feature
            uint32_t lg = (uint32_t)__builtin_amdgcn_ds_bpermute((lane >> 1) << 2, (int)__float_as_uint(slo));
            uint32_t hg = (uint32_t)__builtin_amdgcn_ds_bpermute((lane >> 1) << 2, (int)__float_as_uint(shi));
            accv[rr] = __uint_as_float((lane & 1) ? hg : lg);
        } else {
            // ---------------- rare scalar fallback (k > 64) ----------------
            uint32_t offB = offBr[rr], wBu = wBur[rr];
            float acc0 = selfS[rr] * Xb[(size_t)row * DDIM + lane];
            float acc1 = 0.f, acc2 = 0.f, acc3 = 0.f;
            int e = 0;
            for (; e + 4 <= 64; e += 4) {
                uint32_t o0 = __builtin_amdgcn_readlane(offA, e);
                uint32_t o1 = __builtin_amdgcn_readlane(offA, e + 1);
                uint32_t o2 = __builtin_amdgcn_readlane(offA, e + 2);
                uint32_t o3 = __builtin_amdgcn_readlane(offA, e + 3);
                float w0 = __uint_as_float(__builtin_amdgcn_readlane(wAu, e));
                float w1 = __uint_as_float(__builtin_amdgcn_readlane(wAu, e + 1));
                float w2 = __uint_as_float(__builtin_amdgcn_readlane(wAu, e + 2));
                float w3 = __uint_as_float(__builtin_amdgcn_readlane(wAu, e + 3));
                acc0 = fmaf(w0, *(const float*)(Xc + o0), acc0);
                acc1 = fmaf(w1, *(const float*)(Xc + o1), acc1);
                acc2 = fmaf(w2, *(const float*)(Xc + o2), acc2);
                acc3 = fmaf(w3, *(const float*)(Xc + o3), acc3);
            }
            for (e = 64; e < k; ++e) {
                uint32_t o = __builtin_amdgcn_readlane(offB, e - 64);
                float wv = __uint_as_float(__builtin_amdgcn_readlane(wBu, e - 64));
                acc1 = fmaf(wv, *(const float*)(Xc + o), acc1);
            }
            accv[rr] = (acc0 + acc1) + (acc2 + acc3);
        }
    }

    // fused W-multiply: one WT read serves both rows; 4 partial accs per row
    uint32_t sa = __float_as_uint(accv[0]);
    uint32_t sb = __float_as_uint(accv[1]);
    float ya0 = 0.f, ya1 = 0.f, ya2 = 0.f, ya3 = 0.f;
    float yb0 = 0.f, yb1 = 0.f, yb2 = 0.f, yb3 = 0.f;
    #pragma unroll
    for (int d = 0; d < 64; d += 4) {
        float wt0 = WT[(d + 0) * 65 + lane];
        float wt1 = WT[(d + 1) * 65 + lane];
        float wt2 = WT[(d + 2) * 65 + lane];
        float wt3 = WT[(d + 3) * 65 + lane];
        ya0 = fmaf(__uint_as_float(__builtin_amdgcn_readlane(sa, d + 0)), wt0, ya0);
        ya1 = fmaf(__uint_as_float(__builtin_amdgcn_readlane(sa, d + 1)), wt1, ya1);
        ya2 = fmaf(__uint_as_float(__builtin_amdgcn_readlane(sa, d + 2)), wt2, ya2);
        ya3 = fmaf(__uint_as_float(__builtin_amdgcn_readlane(sa, d + 3)), wt3, ya3);
        yb0 = fmaf(__uint_as_float(__builtin_amdgcn_readlane(sb, d + 0)), wt0, yb0);
        yb1 = fmaf(__uint_as_float(__builtin_amdgcn_readlane(sb, d + 1)), wt1, yb1);
        yb2 = fmaf(__uint_as_float(__builtin_amdgcn_readlane(sb, d + 2)), wt2, yb2);
        yb3 = fmaf(__uint_as_float(__builtin_amdgcn_readlane(sb, d + 3)), wt3, yb3);
    }
    float ya = (ya0 + ya1) + (ya2 + ya3);
    float yb = (yb0 + yb1) + (yb2 + yb3);
    if (dogelu) {
        ya = 0.5f * ya * (1.0f + erff(ya * 0.70710678118654752440f));
        yb = 0.5f * yb * (1.0f + erff(yb * 0.70710678118654752440f));
    }
    Xout[((size_t)b * NNODE + row0)     * DDIM + lane] = ya;
    Xout[((size_t)b * NNODE + row0 + 1) * DDIM + lane] = yb;
}

// ---------------- launch ------------------------------------------------
extern "C" void kernel_launch(void* const* d_in, const int* in_sizes, int n_in,
                              void* d_out, int out_size, void* d_ws, size_t ws_size,
                              hipStream_t stream) {
    const float* H  = (const float*)d_in[0];   // (B,N,D) fp32
    const int*   ei = (const int*)d_in[1];     // (B,2,E) int32
    const float* m  = (const float*)d_in[2];   // (B,E) fp32
    const float* W  = (const float*)d_in[3];   // (L,D,D) fp32
    float* out = (float*)d_out;                // (B,N,D) fp32

    char* ws = (char*)d_ws;
    uint32_t* cnt4    = (uint32_t*)ws;                                        // 512 KB (4 counts/row)
    uint32_t* cnt_fin = (uint32_t*)(ws + (512 << 10));                        // 128 KB
    float*    dis     = (float*)(ws + (640 << 10));                           // 128 KB
    float*    self    = (float*)(ws + (768 << 10));                           // 128 KB
    uint2*    entries = (uint2*)(ws + (896 << 10));                           // 32768*128*8 = 32 MB
    float*    X2      = (float*)(ws + (896 << 10) + (size_t)NROWS * SLOTS * 8);  // 8 MB

    k_build <<<BATCH * (NNODE / RPB) * 4, 512, 0, stream>>>(ei, m, cnt4, entries);
    k_dedupe<<<NROWS / 4, 256, 0, stream>>>(cnt4, entries, cnt_fin, dis, self);
    k_layer <<<4096, 256, 0, stream>>>(H,  W,        X2,  cnt_fin, entries, dis, self, 1);
    k_layer <<<4096, 256, 0, stream>>>(X2, W + 4096, out, cnt_fin, entries, dis, self, 0);
}

// Round 5
// 142.651 us; speedup vs baseline: 1.0524x; 1.0524x over previous
//
#include <hip/hip_runtime.h>
#include <stdint.h>
#include <math.h>

#define BATCH 16
#define NNODE 2048
#define DDIM  64
#define NEDGE 32768
#define SEG   32            // slots per quarter-scan segment (mean 8; P(>32)~1e-11)
#define SLOTS 128           // 4*SEG slots per row
#define NROWS (BATCH*NNODE) // 32768
#define RPB   256           // rows per k_build block (512-thread blocks)

// ---------------- kernel 1: LDS-bucketed edge build (quarter-scan) ------
// v5: RPB 128->256 halves total edge-scans (4.2M vs 8.4M): scans/batch =
// (NNODE/RPB) x E, and RPB is the only lever on that product. LDS 65 KB ->
// 2 blocks/CU x 8 waves = 16 waves/CU (edge list is XCD-local L2-resident,
// so latency cover is still adequate). Everything else identical.
__global__ void k_build(const int* __restrict__ ei, const float* __restrict__ m,
                        uint32_t* __restrict__ cnt4, uint2* __restrict__ entries) {
    __shared__ uint32_t cntS[RPB];
    __shared__ uint32_t keyS[RPB][SEG];   // col | prio<<11
    __shared__ float    valS[RPB][SEG];

    int b  = blockIdx.x & 15;             // batch (XCD-pinned)
    int gh = blockIdx.x >> 4;             // 0..31: row-group*4 + quarter
    int r0 = (gh >> 2) * RPB;             // first owned row
    int q  = gh & 3;                      // which quarter of the edge list
    int t  = threadIdx.x;                 // 0..511

    if (t < RPB) cntS[t] = 0u;
    __syncthreads();

    const int*   eb = ei + (size_t)b * 2 * NEDGE;
    const float* mb = m  + (size_t)b * NEDGE;
    int e0 = q * (NEDGE / 4);

    for (int i = 0; i < 4; ++i) {                  // 4 x 2048 edges (quarter)
        int e4 = e0 + i * 2048 + t * 4;
        int4   s4 = *(const int4*)(eb + e4);
        int4   d4 = *(const int4*)(eb + NEDGE + e4);
        float4 m4 = *(const float4*)(mb + e4);
        #pragma unroll
        for (int j = 0; j < 4; ++j) {
            int   src = j == 0 ? s4.x : j == 1 ? s4.y : j == 2 ? s4.z : s4.w;
            int   dst = j == 0 ? d4.x : j == 1 ? d4.y : j == 2 ? d4.z : d4.w;
            float mv  = j == 0 ? m4.x : j == 1 ? m4.y : j == 2 ? m4.z : m4.w;
            int e  = e4 + j;
            int rs = src - r0;
            if ((unsigned)rs < RPB) {              // row src, col dst, prio e
                uint32_t p = atomicAdd(&cntS[rs], 1u);
                if (p < SEG) { keyS[rs][p] = (uint32_t)dst | ((uint32_t)e << 11); valS[rs][p] = mv; }
            }
            int rd = dst - r0;
            if ((unsigned)rd < RPB) {              // row dst, col src, prio E+e
                uint32_t p = atomicAdd(&cntS[rd], 1u);
                if (p < SEG) { keyS[rd][p] = (uint32_t)src | ((uint32_t)(NEDGE + e) << 11); valS[rd][p] = mv; }
            }
        }
    }
    __syncthreads();

    // coalesced write-out: 8 waves x 32 rows; lanes 0-31 row 2rr, 32-63 row 2rr+1
    int lane = t & 63;
    int wid  = t >> 6;                    // 0..7
    int pos  = lane & 31;
    int sub  = lane >> 5;
    for (int rr = 0; rr < RPB / 16; ++rr) {
        int r  = wid * (RPB / 8) + rr * 2 + sub;
        int rg = b * NNODE + r0 + r;
        int k  = (int)min(cntS[r], (uint32_t)SEG);
        size_t base = (size_t)rg * SLOTS + q * SEG;
        if (pos < k)
            entries[base + pos] = make_uint2(keyS[r][pos], __float_as_uint(valS[r][pos]));
        if (pos == 0) cnt4[rg * 4 + q] = (uint32_t)k;
    }
}

// ---------------- kernel 2: per-row dedupe via LDS scatter-max ----------
// (verbatim from R2 — the -23us win)
__global__ void k_dedupe(const uint32_t* __restrict__ cnt4, uint2* __restrict__ entries,
                         uint32_t* __restrict__ cnt_fin,
                         float* __restrict__ dis, float* __restrict__ self) {
    __shared__ uint32_t tbl[4][NNODE];    // 32 KB: one table per wave
    int b    = blockIdx.x & 15;
    int wv   = threadIdx.x >> 6;
    int w    = b * NNODE + (blockIdx.x >> 4) * 4 + wv;
    int lane = threadIdx.x & 63;
    uint32_t* T = tbl[wv];
    uint4 kq = ((const uint4*)cnt4)[w];
    int k0 = (int)kq.x, k1 = (int)kq.y, k2 = (int)kq.z, k3 = (int)kq.w;
    size_t base = (size_t)w * SLOTS;
    int pos = lane & 31;
    int klo = (lane < 32) ? k0 : k1;
    int khi = (lane < 32) ? k2 : k3;

    uint32_t key0 = 0u, key1 = 0u;
    float v0 = 0.f, v1 = 0.f;
    bool a0 = pos < klo;
    bool a1 = pos < khi;
    if (a0) { uint2 kv = entries[base + lane];      key0 = kv.x; v0 = __uint_as_float(kv.y); }
    if (a1) { uint2 kv = entries[base + 64 + lane]; key1 = kv.x; v1 = __uint_as_float(kv.y); }
    uint32_t c0 = key0 & 2047u, p0 = key0 >> 11;
    uint32_t c1 = key1 & 2047u, p1 = key1 >> 11;

    // clear only the touched slots (LDS is uninitialized garbage otherwise)
    if (a0) T[c0] = 0u;
    if (a1) T[c1] = 0u;
    // scatter-max the priorities
    if (a0) atomicMax(&T[c0], p0);
    if (a1) atomicMax(&T[c1], p1);
    // read back: survivor iff my prio won
    if (a0) a0 = (T[c0] == p0);
    if (a1) a1 = (T[c1] == p1);

    float sum = (a0 ? v0 : 0.f) + (a1 ? v1 : 0.f);
    for (int off = 32; off; off >>= 1) sum += __shfl_xor(sum, off, 64);
    float deg = fmaxf(1.0f + sum, 1e-6f);          // +1: identity diagonal
    if (lane == 0) {
        float di = 1.0f / sqrtf(deg);
        dis[w]  = di;
        self[w] = di * di;
    }

    unsigned long long m0 = __ballot(a0);
    unsigned long long m1 = __ballot(a1);
    unsigned long long below = (1ull << lane) - 1ull;
    int n0 = __popcll(m0);
    if (a0) entries[base + __popcll(m0 & below)]      = make_uint2(key0, __float_as_uint(v0));
    if (a1) entries[base + n0 + __popcll(m1 & below)] = make_uint2(key1, __float_as_uint(v1));
    if (lane == 0) cnt_fin[w] = (uint32_t)(n0 + __popcll(m1));
}

// ---------------- kernel 3: fused SpMM + (X @ W^T) + optional GELU ------
// (reverted to the exact R2 form — best measured, 145.80; three perturbations
// of this kernel read {+5.0, +0.1, +4.3} -> local optimum)
__global__ void k_layer(const float* __restrict__ Xin, const float* __restrict__ W,
                        float* __restrict__ Xout,
                        const uint32_t* __restrict__ cnt_fin, const uint2* __restrict__ entries,
                        const float* __restrict__ dis, const float* __restrict__ self,
                        int dogelu) {
    __shared__ float WT[64 * 65];     // WT[d*65+e] = W[e*64+d]; +1 pad: conflict-free
    int Lb = blockIdx.x;              // 4096 blocks
    int b  = Lb & 15;                 // batch -> XCD swizzle
    int rb = Lb >> 4;
    int t  = threadIdx.x;

    #pragma unroll
    for (int i = 0; i < 16; ++i) {
        int idx = i * 256 + t;
        WT[(idx & 63) * 65 + (idx >> 6)] = W[idx];
    }
    __syncthreads();

    int lane = t & 63;
    int wid  = t >> 6;
    const float* Xb   = Xin + (size_t)b * NNODE * DDIM;
    const char*  Xc   = (const char*)Xb + lane * 4;
    const float* disB = dis + (b << 11);

    float accv[2];
    #pragma unroll
    for (int rr = 0; rr < 2; ++rr) {
        int row = rb * 8 + wid * 2 + rr;
        int rg  = b * NNODE + row;
        int k   = (int)cnt_fin[rg];
        size_t base = (size_t)rg * SLOTS;

        uint32_t kA = 0u, vA = 0u, kB = 0u, vB = 0u;
        if (lane < k)      { uint2 kv = entries[base + lane];      kA = kv.x; vA = kv.y; }
        if (lane + 64 < k) { uint2 kv = entries[base + 64 + lane]; kB = kv.x; vB = kv.y; }

        // in-lane normalization before broadcast: off = col*256, w = dr*val*dis[col]
        float dr = disB[row];
        int   colA = (int)(kA & 2047u);
        uint32_t offA = (uint32_t)colA << 8;
        uint32_t wAu  = __float_as_uint(__uint_as_float(vA) * dr * disB[colA]);
        int   colB = (int)(kB & 2047u);
        uint32_t offB = (uint32_t)colB << 8;
        uint32_t wBu  = __float_as_uint(__uint_as_float(vB) * dr * disB[colB]);

        float acc0 = self[rg] * Xb[(size_t)row * DDIM + lane];   // identity term
        float acc1 = 0.f, acc2 = 0.f, acc3 = 0.f;

        int k0 = k < 64 ? k : 64;
        int e = 0;
        for (; e + 16 <= k0; e += 16) {            // 16 loads in flight
            float xv0, xv1, xv2, xv3, xv4, xv5, xv6, xv7;
            float xv8, xv9, xva, xvb, xvc, xvd, xve, xvf;
            float w0, w1, w2, w3, w4, w5, w6, w7;
            float w8, w9, wa, wb, wc, wd, we, wf;
            #define G(idx, X, Wv) { \
                uint32_t o = __builtin_amdgcn_readlane(offA, e + idx); \
                Wv = __uint_as_float(__builtin_amdgcn_readlane(wAu, e + idx)); \
                X = *(const float*)(Xc + o); }
            G(0, xv0, w0)  G(1, xv1, w1)  G(2, xv2, w2)  G(3, xv3, w3)
            G(4, xv4, w4)  G(5, xv5, w5)  G(6, xv6, w6)  G(7, xv7, w7)
            G(8, xv8, w8)  G(9, xv9, w9)  G(10, xva, wa) G(11, xvb, wb)
            G(12, xvc, wc) G(13, xvd, wd) G(14, xve, we) G(15, xvf, wf)
            #undef G
            acc0 = fmaf(w0, xv0, acc0); acc1 = fmaf(w1, xv1, acc1);
            acc2 = fmaf(w2, xv2, acc2); acc3 = fmaf(w3, xv3, acc3);
            acc0 = fmaf(w4, xv4, acc0); acc1 = fmaf(w5, xv5, acc1);
            acc2 = fmaf(w6, xv6, acc2); acc3 = fmaf(w7, xv7, acc3);
            acc0 = fmaf(w8, xv8, acc0); acc1 = fmaf(w9, xv9, acc1);
            acc2 = fmaf(wa, xva, acc2); acc3 = fmaf(wb, xvb, acc3);
            acc0 = fmaf(wc, xvc, acc0); acc1 = fmaf(wd, xvd, acc1);
            acc2 = fmaf(we, xve, acc2); acc3 = fmaf(wf, xvf, acc3);
        }
        for (; e + 4 <= k0; e += 4) {
            uint32_t o0 = __builtin_amdgcn_readlane(offA, e);
            uint32_t o1 = __builtin_amdgcn_readlane(offA, e + 1);
            uint32_t o2 = __builtin_amdgcn_readlane(offA, e + 2);
            uint32_t o3 = __builtin_amdgcn_readlane(offA, e + 3);
            float w0 = __uint_as_float(__builtin_amdgcn_readlane(wAu, e));
            float w1 = __uint_as_float(__builtin_amdgcn_readlane(wAu, e + 1));
            float w2 = __uint_as_float(__builtin_amdgcn_readlane(wAu, e + 2));
            float w3 = __uint_as_float(__builtin_amdgcn_readlane(wAu, e + 3));
            acc0 = fmaf(w0, *(const float*)(Xc + o0), acc0);
            acc1 = fmaf(w1, *(const float*)(Xc + o1), acc1);
            acc2 = fmaf(w2, *(const float*)(Xc + o2), acc2);
            acc3 = fmaf(w3, *(const float*)(Xc + o3), acc3);
        }
        for (; e < k0; ++e) {
            uint32_t o = __builtin_amdgcn_readlane(offA, e);
            float wv = __uint_as_float(__builtin_amdgcn_readlane(wAu, e));
            acc0 = fmaf(wv, *(const float*)(Xc + o), acc0);
        }
        for (e = 64; e < k; ++e) {                 // rare tail (k>64)
            uint32_t o = __builtin_amdgcn_readlane(offB, e - 64);
            float wv = __uint_as_float(__builtin_amdgcn_readlane(wBu, e - 64));
            acc1 = fmaf(wv, *(const float*)(Xc + o), acc1);
        }
        accv[rr] = (acc0 + acc1) + (acc2 + acc3);
    }

    // fused W-multiply: one WT read serves both rows
    float sa = accv[0], sb = accv[1];
    float ya = 0.f, yb = 0.f;
    #pragma unroll
    for (int d = 0; d < 64; ++d) {
        float wt = WT[d * 65 + lane];
        ya = fmaf(__uint_as_float(__builtin_amdgcn_readlane(__float_as_uint(sa), d)), wt, ya);
        yb = fmaf(__uint_as_float(__builtin_amdgcn_readlane(__float_as_uint(sb), d)), wt, yb);
    }
    if (dogelu) {
        ya = 0.5f * ya * (1.0f + erff(ya * 0.70710678118654752440f));
        yb = 0.5f * yb * (1.0f + erff(yb * 0.70710678118654752440f));
    }
    int row0 = rb * 8 + wid * 2;
    Xout[((size_t)b * NNODE + row0)     * DDIM + lane] = ya;
    Xout[((size_t)b * NNODE + row0 + 1) * DDIM + lane] = yb;
}

// ---------------- launch ------------------------------------------------
extern "C" void kernel_launch(void* const* d_in, const int* in_sizes, int n_in,
                              void* d_out, int out_size, void* d_ws, size_t ws_size,
                              hipStream_t stream) {
    const float* H  = (const float*)d_in[0];   // (B,N,D) fp32
    const int*   ei = (const int*)d_in[1];     // (B,2,E) int32
    const float* m  = (const float*)d_in[2];   // (B,E) fp32
    const float* W  = (const float*)d_in[3];   // (L,D,D) fp32
    float* out = (float*)d_out;                // (B,N,D) fp32

    char* ws = (char*)d_ws;
    uint32_t* cnt4    = (uint32_t*)ws;                                        // 512 KB (4 counts/row)
    uint32_t* cnt_fin = (uint32_t*)(ws + (512 << 10));                        // 128 KB
    float*    dis     = (float*)(ws + (640 << 10));                           // 128 KB
    float*    self    = (float*)(ws + (768 << 10));                           // 128 KB
    uint2*    entries = (uint2*)(ws + (896 << 10));                           // 32768*128*8 = 32 MB
    float*    X2      = (float*)(ws + (896 << 10) + (size_t)NROWS * SLOTS * 8);  // 8 MB

    k_build <<<BATCH * (NNODE / RPB) * 4, 512, 0, stream>>>(ei, m, cnt4, entries);
    k_dedupe<<<NROWS / 4, 256, 0, stream>>>(cnt4, entries, cnt_fin, dis, self);
    k_layer <<<4096, 256, 0, stream>>>(H,  W,        X2,  cnt_fin, entries, dis, self, 1);
    k_layer <<<4096, 256, 0, stream>>>(X2, W + 4096, out, cnt_fin, entries, dis, self, 0);
}

// Round 6
// 142.222 us; speedup vs baseline: 1.0555x; 1.0030x over previous
//
#include <hip/hip_runtime.h>
#include <stdint.h>
#include <math.h>

#define BATCH 16
#define NNODE 2048
#define DDIM  64
#define NEDGE 32768
#define SEG   32            // slots per quarter-scan segment (mean 8; P(>32)~1e-11)
#define SLOTS 128           // 4*SEG slots per row
#define NROWS (BATCH*NNODE) // 32768
#define RPB   512           // rows per k_build block (512-thread blocks)

// ---------------- kernel 1: LDS-bucketed edge build (quarter-scan) ------
// v6: RPB 256->512 halves total edge-scans again (2.1M vs 4.2M). LDS
// 130 KB -> 1 block/CU x 8 waves (grid = 256 blocks = 1/CU, balanced).
// Marginal scan cost measured at ~0.76us/M (R5), so expect ~-1.6us minus
// occupancy penalty. Everything else identical.
__global__ void k_build(const int* __restrict__ ei, const float* __restrict__ m,
                        uint32_t* __restrict__ cnt4, uint2* __restrict__ entries) {
    __shared__ uint32_t cntS[RPB];
    __shared__ uint32_t keyS[RPB][SEG];   // col | prio<<11
    __shared__ float    valS[RPB][SEG];

    int b  = blockIdx.x & 15;             // batch (XCD-pinned)
    int gh = blockIdx.x >> 4;             // row-group*4 + quarter
    int r0 = (gh >> 2) * RPB;             // first owned row
    int q  = gh & 3;                      // which quarter of the edge list
    int t  = threadIdx.x;                 // 0..511

    if (t < RPB) cntS[t] = 0u;
    __syncthreads();

    const int*   eb = ei + (size_t)b * 2 * NEDGE;
    const float* mb = m  + (size_t)b * NEDGE;
    int e0 = q * (NEDGE / 4);

    for (int i = 0; i < 4; ++i) {                  // 4 x 2048 edges (quarter)
        int e4 = e0 + i * 2048 + t * 4;
        int4   s4 = *(const int4*)(eb + e4);
        int4   d4 = *(const int4*)(eb + NEDGE + e4);
        float4 m4 = *(const float4*)(mb + e4);
        #pragma unroll
        for (int j = 0; j < 4; ++j) {
            int   src = j == 0 ? s4.x : j == 1 ? s4.y : j == 2 ? s4.z : s4.w;
            int   dst = j == 0 ? d4.x : j == 1 ? d4.y : j == 2 ? d4.z : d4.w;
            float mv  = j == 0 ? m4.x : j == 1 ? m4.y : j == 2 ? m4.z : m4.w;
            int e  = e4 + j;
            int rs = src - r0;
            if ((unsigned)rs < RPB) {              // row src, col dst, prio e
                uint32_t p = atomicAdd(&cntS[rs], 1u);
                if (p < SEG) { keyS[rs][p] = (uint32_t)dst | ((uint32_t)e << 11); valS[rs][p] = mv; }
            }
            int rd = dst - r0;
            if ((unsigned)rd < RPB) {              // row dst, col src, prio E+e
                uint32_t p = atomicAdd(&cntS[rd], 1u);
                if (p < SEG) { keyS[rd][p] = (uint32_t)src | ((uint32_t)(NEDGE + e) << 11); valS[rd][p] = mv; }
            }
        }
    }
    __syncthreads();

    // coalesced write-out: 8 waves x 64 rows; lanes 0-31 row 2rr, 32-63 row 2rr+1
    int lane = t & 63;
    int wid  = t >> 6;                    // 0..7
    int pos  = lane & 31;
    int sub  = lane >> 5;
    for (int rr = 0; rr < RPB / 16; ++rr) {
        int r  = wid * (RPB / 8) + rr * 2 + sub;
        int rg = b * NNODE + r0 + r;
        int k  = (int)min(cntS[r], (uint32_t)SEG);
        size_t base = (size_t)rg * SLOTS + q * SEG;
        if (pos < k)
            entries[base + pos] = make_uint2(keyS[r][pos], __float_as_uint(valS[r][pos]));
        if (pos == 0) cnt4[rg * 4 + q] = (uint32_t)k;
    }
}

// ---------------- kernel 2: per-row dedupe via LDS scatter-max ----------
// (verbatim from R2 — the -23us win)
__global__ void k_dedupe(const uint32_t* __restrict__ cnt4, uint2* __restrict__ entries,
                         uint32_t* __restrict__ cnt_fin,
                         float* __restrict__ dis, float* __restrict__ self) {
    __shared__ uint32_t tbl[4][NNODE];    // 32 KB: one table per wave
    int b    = blockIdx.x & 15;
    int wv   = threadIdx.x >> 6;
    int w    = b * NNODE + (blockIdx.x >> 4) * 4 + wv;
    int lane = threadIdx.x & 63;
    uint32_t* T = tbl[wv];
    uint4 kq = ((const uint4*)cnt4)[w];
    int k0 = (int)kq.x, k1 = (int)kq.y, k2 = (int)kq.z, k3 = (int)kq.w;
    size_t base = (size_t)w * SLOTS;
    int pos = lane & 31;
    int klo = (lane < 32) ? k0 : k1;
    int khi = (lane < 32) ? k2 : k3;

    uint32_t key0 = 0u, key1 = 0u;
    float v0 = 0.f, v1 = 0.f;
    bool a0 = pos < klo;
    bool a1 = pos < khi;
    if (a0) { uint2 kv = entries[base + lane];      key0 = kv.x; v0 = __uint_as_float(kv.y); }
    if (a1) { uint2 kv = entries[base + 64 + lane]; key1 = kv.x; v1 = __uint_as_float(kv.y); }
    uint32_t c0 = key0 & 2047u, p0 = key0 >> 11;
    uint32_t c1 = key1 & 2047u, p1 = key1 >> 11;

    // clear only the touched slots (LDS is uninitialized garbage otherwise)
    if (a0) T[c0] = 0u;
    if (a1) T[c1] = 0u;
    // scatter-max the priorities
    if (a0) atomicMax(&T[c0], p0);
    if (a1) atomicMax(&T[c1], p1);
    // read back: survivor iff my prio won
    if (a0) a0 = (T[c0] == p0);
    if (a1) a1 = (T[c1] == p1);

    float sum = (a0 ? v0 : 0.f) + (a1 ? v1 : 0.f);
    for (int off = 32; off; off >>= 1) sum += __shfl_xor(sum, off, 64);
    float deg = fmaxf(1.0f + sum, 1e-6f);          // +1: identity diagonal
    if (lane == 0) {
        float di = 1.0f / sqrtf(deg);
        dis[w]  = di;
        self[w] = di * di;
    }

    unsigned long long m0 = __ballot(a0);
    unsigned long long m1 = __ballot(a1);
    unsigned long long below = (1ull << lane) - 1ull;
    int n0 = __popcll(m0);
    if (a0) entries[base + __popcll(m0 & below)]      = make_uint2(key0, __float_as_uint(v0));
    if (a1) entries[base + n0 + __popcll(m1 & below)] = make_uint2(key1, __float_as_uint(v1));
    if (lane == 0) cnt_fin[w] = (uint32_t)(n0 + __popcll(m1));
}

// ---------------- kernel 3: fused SpMM + (X @ W^T) + optional GELU ------
// (verbatim — measured local optimum; perturbations read {+5.0, +0.1, +4.3})
__global__ void k_layer(const float* __restrict__ Xin, const float* __restrict__ W,
                        float* __restrict__ Xout,
                        const uint32_t* __restrict__ cnt_fin, const uint2* __restrict__ entries,
                        const float* __restrict__ dis, const float* __restrict__ self,
                        int dogelu) {
    __shared__ float WT[64 * 65];     // WT[d*65+e] = W[e*64+d]; +1 pad: conflict-free
    int Lb = blockIdx.x;              // 4096 blocks
    int b  = Lb & 15;                 // batch -> XCD swizzle
    int rb = Lb >> 4;
    int t  = threadIdx.x;

    #pragma unroll
    for (int i = 0; i < 16; ++i) {
        int idx = i * 256 + t;
        WT[(idx & 63) * 65 + (idx >> 6)] = W[idx];
    }
    __syncthreads();

    int lane = t & 63;
    int wid  = t >> 6;
    const float* Xb   = Xin + (size_t)b * NNODE * DDIM;
    const char*  Xc   = (const char*)Xb + lane * 4;
    const float* disB = dis + (b << 11);

    float accv[2];
    #pragma unroll
    for (int rr = 0; rr < 2; ++rr) {
        int row = rb * 8 + wid * 2 + rr;
        int rg  = b * NNODE + row;
        int k   = (int)cnt_fin[rg];
        size_t base = (size_t)rg * SLOTS;

        uint32_t kA = 0u, vA = 0u, kB = 0u, vB = 0u;
        if (lane < k)      { uint2 kv = entries[base + lane];      kA = kv.x; vA = kv.y; }
        if (lane + 64 < k) { uint2 kv = entries[base + 64 + lane]; kB = kv.x; vB = kv.y; }

        // in-lane normalization before broadcast: off = col*256, w = dr*val*dis[col]
        float dr = disB[row];
        int   colA = (int)(kA & 2047u);
        uint32_t offA = (uint32_t)colA << 8;
        uint32_t wAu  = __float_as_uint(__uint_as_float(vA) * dr * disB[colA]);
        int   colB = (int)(kB & 2047u);
        uint32_t offB = (uint32_t)colB << 8;
        uint32_t wBu  = __float_as_uint(__uint_as_float(vB) * dr * disB[colB]);

        float acc0 = self[rg] * Xb[(size_t)row * DDIM + lane];   // identity term
        float acc1 = 0.f, acc2 = 0.f, acc3 = 0.f;

        int k0 = k < 64 ? k : 64;
        int e = 0;
        for (; e + 16 <= k0; e += 16) {            // 16 loads in flight
            float xv0, xv1, xv2, xv3, xv4, xv5, xv6, xv7;
            float xv8, xv9, xva, xvb, xvc, xvd, xve, xvf;
            float w0, w1, w2, w3, w4, w5, w6, w7;
            float w8, w9, wa, wb, wc, wd, we, wf;
            #define G(idx, X, Wv) { \
                uint32_t o = __builtin_amdgcn_readlane(offA, e + idx); \
                Wv = __uint_as_float(__builtin_amdgcn_readlane(wAu, e + idx)); \
                X = *(const float*)(Xc + o); }
            G(0, xv0, w0)  G(1, xv1, w1)  G(2, xv2, w2)  G(3, xv3, w3)
            G(4, xv4, w4)  G(5, xv5, w5)  G(6, xv6, w6)  G(7, xv7, w7)
            G(8, xv8, w8)  G(9, xv9, w9)  G(10, xva, wa) G(11, xvb, wb)
            G(12, xvc, wc) G(13, xvd, wd) G(14, xve, we) G(15, xvf, wf)
            #undef G
            acc0 = fmaf(w0, xv0, acc0); acc1 = fmaf(w1, xv1, acc1);
            acc2 = fmaf(w2, xv2, acc2); acc3 = fmaf(w3, xv3, acc3);
            acc0 = fmaf(w4, xv4, acc0); acc1 = fmaf(w5, xv5, acc1);
            acc2 = fmaf(w6, xv6, acc2); acc3 = fmaf(w7, xv7, acc3);
            acc0 = fmaf(w8, xv8, acc0); acc1 = fmaf(w9, xv9, acc1);
            acc2 = fmaf(wa, xva, acc2); acc3 = fmaf(wb, xvb, acc3);
            acc0 = fmaf(wc, xvc, acc0); acc1 = fmaf(wd, xvd, acc1);
            acc2 = fmaf(we, xve, acc2); acc3 = fmaf(wf, xvf, acc3);
        }
        for (; e + 4 <= k0; e += 4) {
            uint32_t o0 = __builtin_amdgcn_readlane(offA, e);
            uint32_t o1 = __builtin_amdgcn_readlane(offA, e + 1);
            uint32_t o2 = __builtin_amdgcn_readlane(offA, e + 2);
            uint32_t o3 = __builtin_amdgcn_readlane(offA, e + 3);
            float w0 = __uint_as_float(__builtin_amdgcn_readlane(wAu, e));
            float w1 = __uint_as_float(__builtin_amdgcn_readlane(wAu, e + 1));
            float w2 = __uint_as_float(__builtin_amdgcn_readlane(wAu, e + 2));
            float w3 = __uint_as_float(__builtin_amdgcn_readlane(wAu, e + 3));
            acc0 = fmaf(w0, *(const float*)(Xc + o0), acc0);
            acc1 = fmaf(w1, *(const float*)(Xc + o1), acc1);
            acc2 = fmaf(w2, *(const float*)(Xc + o2), acc2);
            acc3 = fmaf(w3, *(const float*)(Xc + o3), acc3);
        }
        for (; e < k0; ++e) {
            uint32_t o = __builtin_amdgcn_readlane(offA, e);
            float wv = __uint_as_float(__builtin_amdgcn_readlane(wAu, e));
            acc0 = fmaf(wv, *(const float*)(Xc + o), acc0);
        }
        for (e = 64; e < k; ++e) {                 // rare tail (k>64)
            uint32_t o = __builtin_amdgcn_readlane(offB, e - 64);
            float wv = __uint_as_float(__builtin_amdgcn_readlane(wBu, e - 64));
            acc1 = fmaf(wv, *(const float*)(Xc + o), acc1);
        }
        accv[rr] = (acc0 + acc1) + (acc2 + acc3);
    }

    // fused W-multiply: one WT read serves both rows
    float sa = accv[0], sb = accv[1];
    float ya = 0.f, yb = 0.f;
    #pragma unroll
    for (int d = 0; d < 64; ++d) {
        float wt = WT[d * 65 + lane];
        ya = fmaf(__uint_as_float(__builtin_amdgcn_readlane(__float_as_uint(sa), d)), wt, ya);
        yb = fmaf(__uint_as_float(__builtin_amdgcn_readlane(__float_as_uint(sb), d)), wt, yb);
    }
    if (dogelu) {
        ya = 0.5f * ya * (1.0f + erff(ya * 0.70710678118654752440f));
        yb = 0.5f * yb * (1.0f + erff(yb * 0.70710678118654752440f));
    }
    int row0 = rb * 8 + wid * 2;
    Xout[((size_t)b * NNODE + row0)     * DDIM + lane] = ya;
    Xout[((size_t)b * NNODE + row0 + 1) * DDIM + lane] = yb;
}

// ---------------- launch ------------------------------------------------
extern "C" void kernel_launch(void* const* d_in, const int* in_sizes, int n_in,
                              void* d_out, int out_size, void* d_ws, size_t ws_size,
                              hipStream_t stream) {
    const float* H  = (const float*)d_in[0];   // (B,N,D) fp32
    const int*   ei = (const int*)d_in[1];     // (B,2,E) int32
    const float* m  = (const float*)d_in[2];   // (B,E) fp32
    const float* W  = (const float*)d_in[3];   // (L,D,D) fp32
    float* out = (float*)d_out;                // (B,N,D) fp32

    char* ws = (char*)d_ws;
    uint32_t* cnt4    = (uint32_t*)ws;                                        // 512 KB (4 counts/row)
    uint32_t* cnt_fin = (uint32_t*)(ws + (512 << 10));                        // 128 KB
    float*    dis     = (float*)(ws + (640 << 10));                           // 128 KB
    float*    self    = (float*)(ws + (768 << 10));                           // 128 KB
    uint2*    entries = (uint2*)(ws + (896 << 10));                           // 32768*128*8 = 32 MB
    float*    X2      = (float*)(ws + (896 << 10) + (size_t)NROWS * SLOTS * 8);  // 8 MB

    k_build <<<BATCH * (NNODE / RPB) * 4, 512, 0, stream>>>(ei, m, cnt4, entries);
    k_dedupe<<<NROWS / 4, 256, 0, stream>>>(cnt4, entries, cnt_fin, dis, self);
    k_layer <<<4096, 256, 0, stream>>>(H,  W,        X2,  cnt_fin, entries, dis, self, 1);
    k_layer <<<4096, 256, 0, stream>>>(X2, W + 4096, out, cnt_fin, entries, dis, self, 0);
}